// Round 1
// baseline (801.655 us; speedup 1.0000x reference)
//
#include <hip/hip_runtime.h>
#include <hip/hip_bf16.h>
#include <stdint.h>

#define S_LEN 4096
#define NHEAD 8
#define NEGV  (-1000000000.0f)
#define L2E   1.44269504088896340736f

typedef __attribute__((ext_vector_type(8))) short bf16x8;
typedef __attribute__((ext_vector_type(4))) float f32x4;
typedef unsigned short u16;
typedef unsigned int   u32;

#define MFMA16(a,b,c) __builtin_amdgcn_mfma_f32_16x16x32_bf16((a),(b),(c),0,0,0)
#define EXP2F(x) __builtin_amdgcn_exp2f((x))

__device__ __forceinline__ void gl_lds16(const void* g, void* l) {
  __builtin_amdgcn_global_load_lds((const __attribute__((address_space(1))) void*)g,
                                   (__attribute__((address_space(3))) void*)l, 16, 0, 0);
}

// ws layout (bytes)
#define WS_A1HI 0u
#define WS_A1LO (4u<<20)
#define WS_A2HI (8u<<20)
#define WS_A2LO (12u<<20)
#define WS_VHI  (16u<<20)
#define WS_VLO  (20u<<20)
#define WS_BM   (24u<<20)

// ---- PK1: pack mask (1,1,S,S) int32 -> bitmask bmT[s/32][t] (bit = masked) ----
__global__ void pk_mask(const int* __restrict__ mask, u32* __restrict__ bmT) {
  const int sb = blockIdx.x >> 4;                   // 0..127 (s/32)
  const int t  = (blockIdx.x & 15) * 256 + threadIdx.x;
  u32 w = 0;
  #pragma unroll
  for (int j = 0; j < 32; ++j)
    w |= (mask[(size_t)(sb * 32 + j) * S_LEN + t] != 0 ? 1u : 0u) << j;
  bmT[sb * S_LEN + t] = w;
}

// ---- PK2: A1 fp32 -> bf16 hi/lo, same layout ----
__global__ void pk_split(const float* __restrict__ src, u16* __restrict__ hi, u16* __restrict__ lo) {
  const int i = blockIdx.x * 256 + threadIdx.x;     // x4 floats
  float4 x = ((const float4*)src)[i];
  ushort4 hv, lv;
  #pragma unroll
  for (int j = 0; j < 4; ++j) {
    float xv = ((const float*)&x)[j];
    __hip_bfloat16 hb = __float2bfloat16(xv);
    float hf = __bfloat162float(hb);
    __hip_bfloat16 lb = __float2bfloat16(xv - hf);
    ((u16*)&hv)[j] = *(u16*)&hb;
    ((u16*)&lv)[j] = *(u16*)&lb;
  }
  ((ushort4*)hi)[i] = hv;
  ((ushort4*)lo)[i] = lv;
}

// ---- PK3: 64x64 tile transpose + hi/lo split + XOR pre-swizzle ----
// per (h,ci) tile of 4096 elems: ws[ob+o] = in(c, r),  r=o>>6, c=(o&63)^((r&7)<<3).
// Later: element (r,c) lives at o = r*64 + (c ^ ((r&7)<<3))  -> conflict-free b128 LDS frags.
__global__ void pk_tsplit(const float* __restrict__ src, u16* __restrict__ hi, u16* __restrict__ lo,
                          int chunk_stride, int row_stride) {
  const int h = blockIdx.x >> 6, ci = blockIdx.x & 63;
  const float* base = src + (size_t)h * (S_LEN * 64) + (size_t)ci * chunk_stride;
  __shared__ float tile[64][65];
  const int jr = threadIdx.x & 63, ir = threadIdx.x >> 6;
  #pragma unroll
  for (int p = 0; p < 16; ++p) {
    int i = p * 4 + ir;
    tile[i][jr] = base[(size_t)i * row_stride + jr];
  }
  __syncthreads();
  const size_t ob = (size_t)(h * 64 + ci) * 4096;
  #pragma unroll
  for (int p = 0; p < 16; ++p) {
    int o = p * 256 + threadIdx.x;
    int r = o >> 6;
    int cc = (o & 63) ^ ((r & 7) << 3);
    float xv = tile[cc][r];
    __hip_bfloat16 hb = __float2bfloat16(xv);
    float hf = __bfloat162float(hb);
    __hip_bfloat16 lb = __float2bfloat16(xv - hf);
    hi[ob + o] = *(u16*)&hb;
    lo[ob + o] = *(u16*)&lb;
  }
}

// ---- main fused kernel: scores(bf16x3 MFMA) -> online softmax (pass1) ->
//      recompute + attn write + PV (pass2). WG = 64 s of one head, 4 waves 2sx2t. ----
__launch_bounds__(256, 2)
__global__ void fattn_main(const u16* __restrict__ a1hi, const u16* __restrict__ a1lo,
                           const u16* __restrict__ a2hi, const u16* __restrict__ a2lo,
                           const u16* __restrict__ vhi,  const u16* __restrict__ vlo,
                           const u32* __restrict__ bmT,  float* __restrict__ dout) {
  constexpr int TB = 128, NCH = S_LEN / TB;
  const int h   = blockIdx.x & 7;     // head == XCD (blockIdx % 8 round-robins XCDs)
  const int sb  = blockIdx.x >> 3;    // 0..63
  const int tid = threadIdx.x;
  const int w = tid >> 6, lane = tid & 63;
  const int g = lane >> 4, c = lane & 15;
  const int wsr = w >> 1;             // s-half (0/1)
  const int wth = w & 1;              // t-half (0/1)
  const int sbase = sb * 64 + wsr * 32;
  const int sb32  = sb * 2 + wsr;

  __shared__ __align__(16) char smem[76800];
  u16* st_a2h = (u16*)smem;                     // [2][64][64] swz bf16, 16 KB
  u16* st_a2l = (u16*)(smem + 16384);
  u16* st_vh  = (u16*)(smem + 32768);           // [2][64d][64t] swz
  u16* st_vl  = (u16*)(smem + 49152);
  u16* atb    = (u16*)(smem + 65536);           // [4 waves][32 s][40 t] bf16
  float* mlm  = (float*)(smem + 75776);         // [4][32]
  float* mll  = (float*)(smem + 75776 + 512);   // [4][32]

  // A1 fragments held in regs all kernel: [mt][kk][hi/lo]
  bf16x8 a1f[2][2][2];
  #pragma unroll
  for (int mt = 0; mt < 2; ++mt)
    #pragma unroll
    for (int kk = 0; kk < 2; ++kk) {
      size_t base = (size_t)(h * S_LEN + sbase + mt * 16 + c) * 64 + kk * 32 + g * 8;
      a1f[mt][kk][0] = *(const bf16x8*)(a1hi + base);
      a1f[mt][kk][1] = *(const bf16x8*)(a1lo + base);
    }

  float rm[2][4], rl[2][4];
  #pragma unroll
  for (int mt = 0; mt < 2; ++mt)
    #pragma unroll
    for (int r = 0; r < 4; ++r) { rm[mt][r] = -INFINITY; rl[mt][r] = 0.f; }

  const u32* bmrow = bmT + (size_t)sb32 * S_LEN;

  auto stage16 = [&](u16* dst, const u16* srcb) {
    const char* gsb = (const char*)srcb;
    #pragma unroll
    for (int i = 0; i < 4; ++i) {
      int blk = i * 4 + w;
      gl_lds16(gsb + blk * 1024 + lane * 16, (char*)dst + blk * 1024);
    }
  };

  auto compute_scores = [&](f32x4 (&acc)[2][4]) {
    #pragma unroll
    for (int kk = 0; kk < 2; ++kk)
      #pragma unroll
      for (int nt = 0; nt < 4; ++nt) {
        int eb = wth * 4096 + (nt * 16 + c) * 64 + ((kk * 32 + g * 8) ^ ((c & 7) << 3));
        bf16x8 bh = *(const bf16x8*)(st_a2h + eb);
        bf16x8 bl = *(const bf16x8*)(st_a2l + eb);
        #pragma unroll
        for (int mt = 0; mt < 2; ++mt) {
          acc[mt][nt] = MFMA16(a1f[mt][kk][0], bh, acc[mt][nt]);   // hi*hi
          acc[mt][nt] = MFMA16(a1f[mt][kk][0], bl, acc[mt][nt]);   // hi*lo
          acc[mt][nt] = MFMA16(a1f[mt][kk][1], bh, acc[mt][nt]);   // lo*hi
        }
      }
  };

  // ================= PASS 1: online m / l =================
  #pragma unroll 1
  for (int ci = 0; ci < NCH; ++ci) {
    __syncthreads();
    stage16(st_a2h, a2hi + (size_t)(h * 64 + ci * 2) * 4096);
    stage16(st_a2l, a2lo + (size_t)(h * 64 + ci * 2) * 4096);
    __syncthreads();

    f32x4 acc[2][4];
    #pragma unroll
    for (int mt = 0; mt < 2; ++mt)
      #pragma unroll
      for (int nt = 0; nt < 4; ++nt) acc[mt][nt] = (f32x4){0.f, 0.f, 0.f, 0.f};
    compute_scores(acc);

    u32 mw[4];
    #pragma unroll
    for (int nt = 0; nt < 4; ++nt) mw[nt] = bmrow[ci * TB + wth * 64 + nt * 16 + c];

    float x[2][4][4];
    #pragma unroll
    for (int mt = 0; mt < 2; ++mt)
      #pragma unroll
      for (int nt = 0; nt < 4; ++nt)
        #pragma unroll
        for (int r = 0; r < 4; ++r) {
          float vs = acc[mt][nt][r] * L2E;
          x[mt][nt][r] = ((mw[nt] >> (mt * 16 + g * 4 + r)) & 1u) ? (NEGV * L2E) : vs;
        }

    #pragma unroll
    for (int mt = 0; mt < 2; ++mt)
      #pragma unroll
      for (int r = 0; r < 4; ++r) {
        float mx = fmaxf(fmaxf(x[mt][0][r], x[mt][1][r]), fmaxf(x[mt][2][r], x[mt][3][r]));
        #pragma unroll
        for (int off = 1; off < 16; off <<= 1) mx = fmaxf(mx, __shfl_xor(mx, off));
        float mo = rm[mt][r];
        float mn = fmaxf(mo, mx);
        float alpha = EXP2F(mo - mn);
        float sum = EXP2F(x[mt][0][r] - mn) + EXP2F(x[mt][1][r] - mn)
                  + EXP2F(x[mt][2][r] - mn) + EXP2F(x[mt][3][r] - mn);
        #pragma unroll
        for (int off = 1; off < 16; off <<= 1) sum += __shfl_xor(sum, off);
        rl[mt][r] = rl[mt][r] * alpha + sum;
        rm[mt][r] = mn;
      }
  }

  // merge t-halves (wave w with w^1)
  __syncthreads();
  if (c == 0) {
    #pragma unroll
    for (int mt = 0; mt < 2; ++mt)
      #pragma unroll
      for (int r = 0; r < 4; ++r) {
        mlm[w * 32 + mt * 16 + g * 4 + r] = rm[mt][r];
        mll[w * 32 + mt * 16 + g * 4 + r] = rl[mt][r];
      }
  }
  __syncthreads();
  #pragma unroll
  for (int mt = 0; mt < 2; ++mt)
    #pragma unroll
    for (int r = 0; r < 4; ++r) {
      int sl = mt * 16 + g * 4 + r;
      float m2 = mlm[(w ^ 1) * 32 + sl], l2 = mll[(w ^ 1) * 32 + sl];
      float mo = rm[mt][r];
      float M  = fmaxf(mo, m2);
      float L  = rl[mt][r] * EXP2F(mo - M) + l2 * EXP2F(m2 - M);
      rm[mt][r] = M;
      rl[mt][r] = 1.0f / L;     // rl now holds 1/l
    }

  // ================= PASS 2: attn write + PV =================
  f32x4 oacc[2][4];
  #pragma unroll
  for (int mt = 0; mt < 2; ++mt)
    #pragma unroll
    for (int dt = 0; dt < 4; ++dt) oacc[mt][dt] = (f32x4){0.f, 0.f, 0.f, 0.f};

  float* aout = dout + (size_t)NHEAD * S_LEN * 64;   // attn output base

  #pragma unroll 1
  for (int ci = 0; ci < NCH; ++ci) {
    __syncthreads();
    stage16(st_a2h, a2hi + (size_t)(h * 64 + ci * 2) * 4096);
    stage16(st_a2l, a2lo + (size_t)(h * 64 + ci * 2) * 4096);
    stage16(st_vh,  vhi  + (size_t)(h * 64 + ci * 2) * 4096);
    stage16(st_vl,  vlo  + (size_t)(h * 64 + ci * 2) * 4096);
    __syncthreads();

    f32x4 acc[2][4];
    #pragma unroll
    for (int mt = 0; mt < 2; ++mt)
      #pragma unroll
      for (int nt = 0; nt < 4; ++nt) acc[mt][nt] = (f32x4){0.f, 0.f, 0.f, 0.f};
    compute_scores(acc);

    u32 mw[4];
    #pragma unroll
    for (int nt = 0; nt < 4; ++nt) mw[nt] = bmrow[ci * TB + wth * 64 + nt * 16 + c];

    f32x4 atn[2][4];
    #pragma unroll
    for (int mt = 0; mt < 2; ++mt)
      #pragma unroll
      for (int nt = 0; nt < 4; ++nt)
        #pragma unroll
        for (int r = 0; r < 4; ++r) {
          float vs = acc[mt][nt][r] * L2E;
          float xx = ((mw[nt] >> (mt * 16 + g * 4 + r)) & 1u) ? (NEGV * L2E) : vs;
          atn[mt][nt][r] = EXP2F(xx - rm[mt][r]) * rl[mt][r];
        }

    // coalesced attn store (lane&15 spans contiguous t)
    {
      size_t rowb = (size_t)(h * S_LEN + sbase) * S_LEN + ci * TB + wth * 64;
      #pragma unroll
      for (int mt = 0; mt < 2; ++mt)
        #pragma unroll
        for (int nt = 0; nt < 4; ++nt)
          #pragma unroll
          for (int r = 0; r < 4; ++r)
            aout[rowb + (size_t)(mt * 16 + g * 4 + r) * S_LEN + nt * 16 + c] = atn[mt][nt][r];
    }

    // PV: transpose attn->bf16 via per-wave LDS buf, 2 k-steps of 32 t
    u16* myatb = atb + w * 1280;
    #pragma unroll
    for (int kk2 = 0; kk2 < 2; ++kk2) {
      #pragma unroll
      for (int mt = 0; mt < 2; ++mt)
        #pragma unroll
        for (int ntl = 0; ntl < 2; ++ntl)
          #pragma unroll
          for (int r = 0; r < 4; ++r) {
            __hip_bfloat16 hb = __float2bfloat16(atn[mt][kk2 * 2 + ntl][r]);
            myatb[(mt * 16 + g * 4 + r) * 40 + ntl * 16 + c] = *(u16*)&hb;
          }
      bf16x8 af[2];
      #pragma unroll
      for (int mt = 0; mt < 2; ++mt)
        af[mt] = *(const bf16x8*)(myatb + (mt * 16 + c) * 40 + g * 8);
      #pragma unroll
      for (int dt = 0; dt < 4; ++dt) {
        int ve = wth * 4096 + (dt * 16 + c) * 64 + ((kk2 * 32 + g * 8) ^ ((c & 7) << 3));
        bf16x8 bvh = *(const bf16x8*)(st_vh + ve);
        bf16x8 bvl = *(const bf16x8*)(st_vl + ve);
        #pragma unroll
        for (int mt = 0; mt < 2; ++mt) {
          oacc[mt][dt] = MFMA16(af[mt], bvh, oacc[mt][dt]);
          oacc[mt][dt] = MFMA16(af[mt], bvl, oacc[mt][dt]);
        }
      }
    }
  }

  // epilogue: merge t-half partial outputs, store
  __syncthreads();
  float* outx = (float*)smem;            // [2][32][66] f32, aliases staging
  if (wth == 1) {
    #pragma unroll
    for (int mt = 0; mt < 2; ++mt)
      #pragma unroll
      for (int dt = 0; dt < 4; ++dt)
        #pragma unroll
        for (int r = 0; r < 4; ++r)
          outx[wsr * 2112 + (mt * 16 + g * 4 + r) * 66 + dt * 16 + c] = oacc[mt][dt][r];
  }
  __syncthreads();
  if (wth == 0) {
    #pragma unroll
    for (int mt = 0; mt < 2; ++mt)
      #pragma unroll
      for (int dt = 0; dt < 4; ++dt)
        #pragma unroll
        for (int r = 0; r < 4; ++r) {
          float vv = oacc[mt][dt][r] + outx[wsr * 2112 + (mt * 16 + g * 4 + r) * 66 + dt * 16 + c];
          int s = sbase + mt * 16 + g * 4 + r;
          dout[(size_t)(h * S_LEN + s) * 64 + dt * 16 + c] = vv;
        }
  }
}

extern "C" void kernel_launch(void* const* d_in, const int* in_sizes, int n_in,
                              void* d_out, int out_size, void* d_ws, size_t ws_size,
                              hipStream_t stream) {
  (void)in_sizes; (void)n_in; (void)out_size; (void)ws_size;
  const float* v    = (const float*)d_in[0];
  const float* A1   = (const float*)d_in[1];
  const float* A2   = (const float*)d_in[2];
  const int*   mask = (const int*)d_in[3];
  float* out = (float*)d_out;
  char* ws = (char*)d_ws;

  u16* a1hi = (u16*)(ws + WS_A1HI);
  u16* a1lo = (u16*)(ws + WS_A1LO);
  u16* a2hi = (u16*)(ws + WS_A2HI);
  u16* a2lo = (u16*)(ws + WS_A2LO);
  u16* vhi  = (u16*)(ws + WS_VHI);
  u16* vlo  = (u16*)(ws + WS_VLO);
  u32* bmT  = (u32*)(ws + WS_BM);

  pk_mask  <<<2048, 256, 0, stream>>>(mask, bmT);
  pk_split <<<2048, 256, 0, stream>>>(A1, a1hi, a1lo);
  pk_tsplit<<<512,  256, 0, stream>>>(A2, a2hi, a2lo, 64, 4096);   // A2[f][t] -> [t][f]
  pk_tsplit<<<512,  256, 0, stream>>>(v,  vhi,  vlo,  4096, 64);   // v[t][d]  -> [d][t]
  fattn_main<<<512, 256, 0, stream>>>(a1hi, a1lo, a2hi, a2lo, vhi, vlo, bmT, out);
}